// Round 1
// baseline (1535.257 us; speedup 1.0000x reference)
//
#include <hip/hip_runtime.h>
#include <math.h>

// Problem constants
#define B_  8
#define L_  128
#define V_  32000
#define D_  64
#define R1_ 128
#define R2_ 320
#define UP_ 640

// ---------------------------------------------------------------------------
// pe_kernel: out[l,o] = relu(b[o] + sum_m P[l,m]*W[o,m]) with P = pos_enc(L,dEnc)
// grid: 128 (l), block: 256
__global__ __launch_bounds__(256) void pe_kernel(const float* __restrict__ W,
                                                 const float* __restrict__ bias,
                                                 float* __restrict__ out,
                                                 int outF, int dEnc) {
    __shared__ float P[640];
    int l = blockIdx.x;
    int t = threadIdx.x;
    for (int m = t; m < dEnc; m += 256) {
        int i = m >> 1;
        float ang = (float)l * powf(10000.0f, -2.0f * (float)i / (float)dEnc);
        P[m] = (m & 1) ? cosf(ang) : sinf(ang);
    }
    __syncthreads();
    for (int o = t; o < outF; o += 256) {
        float acc = bias[o];
        const float* w = W + (size_t)o * dEnc;
        for (int m = 0; m < dEnc; ++m) acc = fmaf(P[m], w[m], acc);
        out[l * outF + o] = fmaxf(acc, 0.f);
    }
}

// ---------------------------------------------------------------------------
// Stage A (split-K): partA[split][row][d] = sum_{k in split} x[row,k]*W_emb[d,k]
// grid: (32 rowblocks, 8 ksplits), block: 256 (64 d-cols x 4 rowgroups of 8)
#define TM_ 32
__global__ __launch_bounds__(256) void embA_kernel(const float* __restrict__ x,
                                                   const float* __restrict__ Wemb,
                                                   float* __restrict__ partA) {
    __shared__ float xs[TM_ * 500];  // 64000 B
    int t = threadIdx.x;
    int c = t & 63;    // output dim d
    int rg = t >> 6;   // row group 0..3 (wave id -> LDS broadcast)
    int rowbase = blockIdx.x * TM_;
    int split = blockIdx.y;
    float acc[8];
#pragma unroll
    for (int q = 0; q < 8; ++q) acc[q] = 0.f;

    for (int ch = 0; ch < 8; ++ch) {
        int k0 = split * 4000 + ch * 500;
        __syncthreads();
        for (int idx = t; idx < TM_ * 500; idx += 256) {
            int r = idx / 500;
            int k = idx - r * 500;
            xs[idx] = x[(size_t)(rowbase + r) * 32000 + k0 + k];
        }
        __syncthreads();
        const float4* wp = (const float4*)(Wemb + (size_t)c * 32000 + k0);
        for (int k4 = 0; k4 < 125; ++k4) {
            float4 w = wp[k4];
#pragma unroll
            for (int q = 0; q < 8; ++q) {
                float4 xv = *(const float4*)&xs[(rg * 8 + q) * 500 + k4 * 4];
                acc[q] = fmaf(xv.x, w.x, acc[q]);
                acc[q] = fmaf(xv.y, w.y, acc[q]);
                acc[q] = fmaf(xv.z, w.z, acc[q]);
                acc[q] = fmaf(xv.w, w.w, acc[q]);
            }
        }
    }
#pragma unroll
    for (int q = 0; q < 8; ++q) {
        int row = rowbase + rg * 8 + q;
        partA[((size_t)split * 1024 + row) * 64 + c] = acc[q];
    }
}

// ---------------------------------------------------------------------------
// reduceA: h1[row,d] = relu(sum_s partA + b_emb[d]) + pe1[l,d]; s1[row]=sum_d h1
// grid: 1024 (row), block: 64
__global__ __launch_bounds__(64) void reduceA_kernel(const float* __restrict__ partA,
                                                     const float* __restrict__ bemb,
                                                     const float* __restrict__ pe1,
                                                     float* __restrict__ h1,
                                                     float* __restrict__ s1) {
    int row = blockIdx.x;
    int d = threadIdx.x;
    int l = row & 127;
    float v = bemb[d];
#pragma unroll
    for (int s = 0; s < 8; ++s) v += partA[((size_t)s * 1024 + row) * 64 + d];
    v = fmaxf(v, 0.f) + pe1[l * 64 + d];
    h1[row * 64 + d] = v;
    float sum = v;
    for (int off = 32; off > 0; off >>= 1) sum += __shfl_down(sum, off);
    if (d == 0) s1[row] = sum;
}

// ---------------------------------------------------------------------------
// wr1: Wr1[b,r,j] = sum_k s1[b,k] * W_red[r, k*64+j]
// grid: 128 (r), block: 64 (j)
__global__ __launch_bounds__(64) void wr1_kernel(const float* __restrict__ Wred,
                                                 const float* __restrict__ s1,
                                                 float* __restrict__ Wr1) {
    __shared__ float ss[8 * 128];
    int r = blockIdx.x;
    int j = threadIdx.x;
    for (int idx = j; idx < 1024; idx += 64) ss[idx] = s1[idx];
    __syncthreads();
    float acc[8];
#pragma unroll
    for (int b = 0; b < 8; ++b) acc[b] = 0.f;
    const float* w = Wred + (size_t)r * 8192 + j;
    for (int k = 0; k < 128; ++k) {
        float wv = w[k * 64];
#pragma unroll
        for (int b = 0; b < 8; ++b) acc[b] = fmaf(ss[b * 128 + k], wv, acc[b]);
    }
#pragma unroll
    for (int b = 0; b < 8; ++b) Wr1[((size_t)b * 128 + r) * 64 + j] = acc[b];
}

// ---------------------------------------------------------------------------
// h2: h2[b,i,r] = relu(sum_j h1[b,i,j]*Wr1[b,r,j] + b_red[r]) + pe2[i,r]; s2=sum_r
// grid: 1024 (row=(b,i)), block: 128 (r)
__global__ __launch_bounds__(128) void h2_kernel(const float* __restrict__ h1,
                                                 const float* __restrict__ Wr1,
                                                 const float* __restrict__ bred,
                                                 const float* __restrict__ pe2,
                                                 float* __restrict__ h2,
                                                 float* __restrict__ s2) {
    __shared__ float hrow[64];
    __shared__ float red[2];
    int row = blockIdx.x;
    int b = row >> 7, i = row & 127;
    int r = threadIdx.x;
    if (r < 64) hrow[r] = h1[row * 64 + r];
    __syncthreads();
    float acc = bred[r];
    const float4* w = (const float4*)(Wr1 + ((size_t)b * 128 + r) * 64);
#pragma unroll
    for (int j4 = 0; j4 < 16; ++j4) {
        float4 wv = w[j4];
        float4 hv = *(const float4*)&hrow[j4 * 4];
        acc = fmaf(hv.x, wv.x, acc);
        acc = fmaf(hv.y, wv.y, acc);
        acc = fmaf(hv.z, wv.z, acc);
        acc = fmaf(hv.w, wv.w, acc);
    }
    float val = fmaxf(acc, 0.f) + pe2[i * 128 + r];
    h2[row * 128 + r] = val;
    float sum = val;
    for (int off = 32; off > 0; off >>= 1) sum += __shfl_down(sum, off);
    if ((r & 63) == 0) red[r >> 6] = sum;
    __syncthreads();
    if (r == 0) s2[row] = red[0] + red[1];
}

// ---------------------------------------------------------------------------
// wr2: Wr2[b,r2,j] = sum_k s2[b,k] * W_red2[r2, k*128+j]
// grid: 320 (r2), block: 128 (j)
__global__ __launch_bounds__(128) void wr2_kernel(const float* __restrict__ Wred2,
                                                  const float* __restrict__ s2,
                                                  float* __restrict__ Wr2) {
    __shared__ float ss[8 * 128];
    int r = blockIdx.x;
    int j = threadIdx.x;
    for (int idx = j; idx < 1024; idx += 128) ss[idx] = s2[idx];
    __syncthreads();
    float acc[8];
#pragma unroll
    for (int b = 0; b < 8; ++b) acc[b] = 0.f;
    const float* w = Wred2 + (size_t)r * 16384 + j;
    for (int k = 0; k < 128; ++k) {
        float wv = w[k * 128];
#pragma unroll
        for (int b = 0; b < 8; ++b) acc[b] = fmaf(ss[b * 128 + k], wv, acc[b]);
    }
#pragma unroll
    for (int b = 0; b < 8; ++b) Wr2[((size_t)b * 320 + r) * 128 + j] = acc[b];
}

// ---------------------------------------------------------------------------
// h3: h3[b,i,r2] = relu(sum_j h2[b,i,j]*Wr2[b,r2,j] + b_red2[r2]) + pe3[i,r2]
// grid: 1024 (row), block: 320 (r2)
__global__ __launch_bounds__(320) void h3_kernel(const float* __restrict__ h2,
                                                 const float* __restrict__ Wr2,
                                                 const float* __restrict__ bred2,
                                                 const float* __restrict__ pe3,
                                                 float* __restrict__ h3) {
    __shared__ float hrow[128];
    int row = blockIdx.x;
    int b = row >> 7, i = row & 127;
    int r = threadIdx.x;
    if (r < 128) hrow[r] = h2[row * 128 + r];
    __syncthreads();
    float acc = bred2[r];
    const float4* w = (const float4*)(Wr2 + ((size_t)b * 320 + r) * 128);
#pragma unroll
    for (int j4 = 0; j4 < 32; ++j4) {
        float4 wv = w[j4];
        float4 hv = *(const float4*)&hrow[j4 * 4];
        acc = fmaf(hv.x, wv.x, acc);
        acc = fmaf(hv.y, wv.y, acc);
        acc = fmaf(hv.z, wv.z, acc);
        acc = fmaf(hv.w, wv.w, acc);
    }
    h3[(size_t)row * 320 + r] = fmaxf(acc, 0.f) + pe3[i * 320 + r];
}

// ---------------------------------------------------------------------------
// h4: h4[row,u] = relu(sum_r2 h3[row,r2]*W_up1[u,r2] + b_up1[u])
// grid: 128 (rowgroups of 8), block: 320; each thread does u=t and u=t+320
__global__ __launch_bounds__(320) void h4_kernel(const float* __restrict__ h3,
                                                 const float* __restrict__ Wup1,
                                                 const float* __restrict__ bup1,
                                                 float* __restrict__ h4) {
    __shared__ float hs[8 * 320];
    int rowbase = blockIdx.x * 8;
    int t = threadIdx.x;
    for (int idx = t; idx < 8 * 320; idx += 320) hs[idx] = h3[(size_t)rowbase * 320 + idx];
    __syncthreads();
    for (int uu = 0; uu < 2; ++uu) {
        int u = t + uu * 320;
        float bias = bup1[u];
        float acc[8];
#pragma unroll
        for (int q = 0; q < 8; ++q) acc[q] = bias;
        const float4* w = (const float4*)(Wup1 + (size_t)u * 320);
        for (int j4 = 0; j4 < 80; ++j4) {
            float4 wv = w[j4];
#pragma unroll
            for (int q = 0; q < 8; ++q) {
                float4 hv = *(const float4*)&hs[q * 320 + j4 * 4];
                acc[q] = fmaf(hv.x, wv.x, acc[q]);
                acc[q] = fmaf(hv.y, wv.y, acc[q]);
                acc[q] = fmaf(hv.z, wv.z, acc[q]);
                acc[q] = fmaf(hv.w, wv.w, acc[q]);
            }
        }
#pragma unroll
        for (int q = 0; q < 8; ++q)
            h4[((size_t)rowbase + q) * 640 + u] = fmaxf(acc[q], 0.f);
    }
}

// ---------------------------------------------------------------------------
// final: out[b,v] = relu(b_fin + sum_l Wfin[l]*relu(b_up2[v] + sum_u h4[b,l,u]*W_up2[v,u]))
// grid: (500 vtiles, 8 b), block: 256 (64 v x 4 l-groups of 32)
#define UC_ 64
__global__ __launch_bounds__(256) void final_kernel(const float* __restrict__ h4,
                                                    const float* __restrict__ Wup2,
                                                    const float* __restrict__ bup2,
                                                    const float* __restrict__ Wfin,
                                                    const float* __restrict__ bfin,
                                                    float* __restrict__ out) {
    __shared__ float hs[128 * UC_];  // 32 KB
    __shared__ float red[4][64];
    int b = blockIdx.y;
    int v0 = blockIdx.x * 64;
    int t = threadIdx.x;
    int v = t & 63;
    int lg = t >> 6;  // wave id -> l-group (LDS broadcast within wave)
    float acc[32];
#pragma unroll
    for (int q = 0; q < 32; ++q) acc[q] = 0.f;
    const float* wrow = Wup2 + (size_t)(v0 + v) * 640;

    for (int ch = 0; ch < 10; ++ch) {
        int u0 = ch * UC_;
        __syncthreads();
        for (int idx = t; idx < 128 * UC_; idx += 256) {
            int l = idx >> 6;
            int u = idx & 63;
            hs[idx] = h4[((size_t)b * 128 + l) * 640 + u0 + u];
        }
        __syncthreads();
        const float4* wp = (const float4*)(wrow + u0);
        for (int k4 = 0; k4 < UC_ / 4; ++k4) {
            float4 wv = wp[k4];
#pragma unroll
            for (int q = 0; q < 32; ++q) {
                float4 hv = *(const float4*)&hs[(lg * 32 + q) * UC_ + k4 * 4];
                acc[q] = fmaf(hv.x, wv.x, acc[q]);
                acc[q] = fmaf(hv.y, wv.y, acc[q]);
                acc[q] = fmaf(hv.z, wv.z, acc[q]);
                acc[q] = fmaf(hv.w, wv.w, acc[q]);
            }
        }
    }
    float bias = bup2[v0 + v];
    float psum = 0.f;
#pragma unroll
    for (int q = 0; q < 32; ++q) {
        int l = lg * 32 + q;
        psum += Wfin[l] * fmaxf(acc[q] + bias, 0.f);
    }
    red[lg][v] = psum;
    __syncthreads();
    if (t < 64) {
        float tot = red[0][t] + red[1][t] + red[2][t] + red[3][t] + bfin[0];
        out[(size_t)b * 32000 + v0 + t] = fmaxf(tot, 0.f);
    }
}

// ---------------------------------------------------------------------------
extern "C" void kernel_launch(void* const* d_in, const int* in_sizes, int n_in,
                              void* d_out, int out_size, void* d_ws, size_t ws_size,
                              hipStream_t stream) {
    const float* x      = (const float*)d_in[0];
    const float* W_emb  = (const float*)d_in[1];
    const float* b_emb  = (const float*)d_in[2];
    const float* W_pos1 = (const float*)d_in[3];
    const float* b_pos1 = (const float*)d_in[4];
    const float* W_red  = (const float*)d_in[5];
    const float* b_red  = (const float*)d_in[6];
    const float* W_pos2 = (const float*)d_in[7];
    const float* b_pos2 = (const float*)d_in[8];
    const float* W_red2 = (const float*)d_in[9];
    const float* b_red2 = (const float*)d_in[10];
    const float* W_pos3 = (const float*)d_in[11];
    const float* b_pos3 = (const float*)d_in[12];
    const float* W_up1  = (const float*)d_in[13];
    const float* b_up1  = (const float*)d_in[14];
    const float* W_up2  = (const float*)d_in[15];
    const float* b_up2  = (const float*)d_in[16];
    const float* W_fin  = (const float*)d_in[17];
    const float* b_fin  = (const float*)d_in[18];
    float* out = (float*)d_out;

    float* ws  = (float*)d_ws;
    float* pe1 = ws;              // 8192
    float* pe2 = pe1 + 8192;      // 16384
    float* pe3 = pe2 + 16384;     // 40960
    float* h1  = pe3 + 40960;     // 65536
    float* s1  = h1 + 65536;      // 1024
    float* Wr1 = s1 + 1024;       // 65536
    float* h2  = Wr1 + 65536;     // 131072
    float* s2  = h2 + 131072;     // 1024
    float* Wr2 = s2 + 1024;       // 327680
    float* h3  = Wr2 + 327680;    // 327680
    float* h4  = h3 + 327680;     // 655360
    float* partA = h4 + 655360;   // 524288
    // total: 2,164,736 floats = ~8.7 MB of ws

    pe_kernel<<<dim3(128), 256, 0, stream>>>(W_pos1, b_pos1, pe1, 64, 128);
    pe_kernel<<<dim3(128), 256, 0, stream>>>(W_pos2, b_pos2, pe2, 128, 256);
    pe_kernel<<<dim3(128), 256, 0, stream>>>(W_pos3, b_pos3, pe3, 320, 640);
    embA_kernel<<<dim3(32, 8), 256, 0, stream>>>(x, W_emb, partA);
    reduceA_kernel<<<dim3(1024), 64, 0, stream>>>(partA, b_emb, pe1, h1, s1);
    wr1_kernel<<<dim3(128), 64, 0, stream>>>(W_red, s1, Wr1);
    h2_kernel<<<dim3(1024), 128, 0, stream>>>(h1, Wr1, b_red, pe2, h2, s2);
    wr2_kernel<<<dim3(320), 128, 0, stream>>>(W_red2, s2, Wr2);
    h3_kernel<<<dim3(1024), 320, 0, stream>>>(h2, Wr2, b_red2, pe3, h3);
    h4_kernel<<<dim3(128), 320, 0, stream>>>(h3, W_up1, b_up1, h4);
    final_kernel<<<dim3(500, 8), 256, 0, stream>>>(h4, W_up2, b_up2, W_fin, b_fin, out);
}

// Round 2
// 740.144 us; speedup vs baseline: 2.0743x; 2.0743x over previous
//
#include <hip/hip_runtime.h>
#include <hip/hip_bf16.h>
#include <math.h>

// Problem constants
#define B_  8
#define L_  128
#define V_  32000
#define D_  64
#define R1_ 128
#define R2_ 320
#define UP_ 640

typedef short bf16x8 __attribute__((ext_vector_type(8)));
typedef float f32x4 __attribute__((ext_vector_type(4)));

#define GLDS16(gp, lp)                                                         \
    __builtin_amdgcn_global_load_lds(                                          \
        (const __attribute__((address_space(1))) void*)(gp),                   \
        (__attribute__((address_space(3))) void*)(lp), 16, 0, 0)

static __device__ inline unsigned short f2bf(float x) {
    __hip_bfloat16 h = __float2bfloat16(x);
    return *reinterpret_cast<unsigned short*>(&h);
}

// ---------------------------------------------------------------------------
// pe_kernel: out[l,o] = relu(b[o] + sum_m P[l,m]*W[o,m]) with P = pos_enc(L,dEnc)
__global__ __launch_bounds__(256) void pe_kernel(const float* __restrict__ W,
                                                 const float* __restrict__ bias,
                                                 float* __restrict__ out,
                                                 int outF, int dEnc) {
    __shared__ float P[640];
    int l = blockIdx.x;
    int t = threadIdx.x;
    for (int m = t; m < dEnc; m += 256) {
        int i = m >> 1;
        float ang = (float)l * powf(10000.0f, -2.0f * (float)i / (float)dEnc);
        P[m] = (m & 1) ? cosf(ang) : sinf(ang);
    }
    __syncthreads();
    for (int o = t; o < outF; o += 256) {
        float acc = bias[o];
        const float* w = W + (size_t)o * dEnc;
        for (int m = 0; m < dEnc; ++m) acc = fmaf(P[m], w[m], acc);
        out[l * outF + o] = fmaxf(acc, 0.f);
    }
}

// ---------------------------------------------------------------------------
// Stage A (split-K): partA[split][row][d] = sum_{k in split} x[row,k]*W_emb[d,k]
#define TM_ 32
__global__ __launch_bounds__(256) void embA_kernel(const float* __restrict__ x,
                                                   const float* __restrict__ Wemb,
                                                   float* __restrict__ partA) {
    __shared__ float xs[TM_ * 500];  // 64000 B
    int t = threadIdx.x;
    int c = t & 63;    // output dim d
    int rg = t >> 6;   // row group 0..3
    int rowbase = blockIdx.x * TM_;
    int split = blockIdx.y;
    float acc[8];
#pragma unroll
    for (int q = 0; q < 8; ++q) acc[q] = 0.f;

    for (int ch = 0; ch < 8; ++ch) {
        int k0 = split * 4000 + ch * 500;
        __syncthreads();
        for (int idx = t; idx < TM_ * 500; idx += 256) {
            int r = idx / 500;
            int k = idx - r * 500;
            xs[idx] = x[(size_t)(rowbase + r) * 32000 + k0 + k];
        }
        __syncthreads();
        const float4* wp = (const float4*)(Wemb + (size_t)c * 32000 + k0);
        for (int k4 = 0; k4 < 125; ++k4) {
            float4 w = wp[k4];
#pragma unroll
            for (int q = 0; q < 8; ++q) {
                float4 xv = *(const float4*)&xs[(rg * 8 + q) * 500 + k4 * 4];
                acc[q] = fmaf(xv.x, w.x, acc[q]);
                acc[q] = fmaf(xv.y, w.y, acc[q]);
                acc[q] = fmaf(xv.z, w.z, acc[q]);
                acc[q] = fmaf(xv.w, w.w, acc[q]);
            }
        }
    }
#pragma unroll
    for (int q = 0; q < 8; ++q) {
        int row = rowbase + rg * 8 + q;
        partA[((size_t)split * 1024 + row) * 64 + c] = acc[q];
    }
}

// ---------------------------------------------------------------------------
// reduceA: h1[row,d] = relu(sum_s partA + b_emb[d]) + pe1[l,d]; s1[row]=sum_d h1
__global__ __launch_bounds__(64) void reduceA_kernel(const float* __restrict__ partA,
                                                     const float* __restrict__ bemb,
                                                     const float* __restrict__ pe1,
                                                     float* __restrict__ h1,
                                                     float* __restrict__ s1) {
    int row = blockIdx.x;
    int d = threadIdx.x;
    int l = row & 127;
    float v = bemb[d];
#pragma unroll
    for (int s = 0; s < 8; ++s) v += partA[((size_t)s * 1024 + row) * 64 + d];
    v = fmaxf(v, 0.f) + pe1[l * 64 + d];
    h1[row * 64 + d] = v;
    float sum = v;
    for (int off = 32; off > 0; off >>= 1) sum += __shfl_down(sum, off);
    if (d == 0) s1[row] = sum;
}

// ---------------------------------------------------------------------------
// wr1: Wr1[b,r,j] = sum_k s1[b,k] * W_red[r, k*64+j]
__global__ __launch_bounds__(64) void wr1_kernel(const float* __restrict__ Wred,
                                                 const float* __restrict__ s1,
                                                 float* __restrict__ Wr1) {
    __shared__ float ss[8 * 128];
    int r = blockIdx.x;
    int j = threadIdx.x;
    for (int idx = j; idx < 1024; idx += 64) ss[idx] = s1[idx];
    __syncthreads();
    float acc[8];
#pragma unroll
    for (int b = 0; b < 8; ++b) acc[b] = 0.f;
    const float* w = Wred + (size_t)r * 8192 + j;
    for (int k = 0; k < 128; ++k) {
        float wv = w[k * 64];
#pragma unroll
        for (int b = 0; b < 8; ++b) acc[b] = fmaf(ss[b * 128 + k], wv, acc[b]);
    }
#pragma unroll
    for (int b = 0; b < 8; ++b) Wr1[((size_t)b * 128 + r) * 64 + j] = acc[b];
}

// ---------------------------------------------------------------------------
// h2: h2[b,i,r] = relu(sum_j h1[b,i,j]*Wr1[b,r,j] + b_red[r]) + pe2[i,r]; s2=sum_r
__global__ __launch_bounds__(128) void h2_kernel(const float* __restrict__ h1,
                                                 const float* __restrict__ Wr1,
                                                 const float* __restrict__ bred,
                                                 const float* __restrict__ pe2,
                                                 float* __restrict__ h2,
                                                 float* __restrict__ s2) {
    __shared__ float hrow[64];
    __shared__ float red[2];
    int row = blockIdx.x;
    int b = row >> 7, i = row & 127;
    int r = threadIdx.x;
    if (r < 64) hrow[r] = h1[row * 64 + r];
    __syncthreads();
    float acc = bred[r];
    const float4* w = (const float4*)(Wr1 + ((size_t)b * 128 + r) * 64);
#pragma unroll
    for (int j4 = 0; j4 < 16; ++j4) {
        float4 wv = w[j4];
        float4 hv = *(const float4*)&hrow[j4 * 4];
        acc = fmaf(hv.x, wv.x, acc);
        acc = fmaf(hv.y, wv.y, acc);
        acc = fmaf(hv.z, wv.z, acc);
        acc = fmaf(hv.w, wv.w, acc);
    }
    float val = fmaxf(acc, 0.f) + pe2[i * 128 + r];
    h2[row * 128 + r] = val;
    float sum = val;
    for (int off = 32; off > 0; off >>= 1) sum += __shfl_down(sum, off);
    if ((r & 63) == 0) red[r >> 6] = sum;
    __syncthreads();
    if (r == 0) s2[row] = red[0] + red[1];
}

// ---------------------------------------------------------------------------
// wr2: Wr2[b,r2,j] = sum_k s2[b,k] * W_red2[r2, k*128+j]
__global__ __launch_bounds__(128) void wr2_kernel(const float* __restrict__ Wred2,
                                                  const float* __restrict__ s2,
                                                  float* __restrict__ Wr2) {
    __shared__ float ss[8 * 128];
    int r = blockIdx.x;
    int j = threadIdx.x;
    for (int idx = j; idx < 1024; idx += 128) ss[idx] = s2[idx];
    __syncthreads();
    float acc[8];
#pragma unroll
    for (int b = 0; b < 8; ++b) acc[b] = 0.f;
    const float* w = Wred2 + (size_t)r * 16384 + j;
    for (int k = 0; k < 128; ++k) {
        float wv = w[k * 128];
#pragma unroll
        for (int b = 0; b < 8; ++b) acc[b] = fmaf(ss[b * 128 + k], wv, acc[b]);
    }
#pragma unroll
    for (int b = 0; b < 8; ++b) Wr2[((size_t)b * 320 + r) * 128 + j] = acc[b];
}

// ---------------------------------------------------------------------------
// h3: h3[b,i,r2] = relu(sum_j h2[b,i,j]*Wr2[b,r2,j] + b_red2[r2]) + pe3[i,r2]
__global__ __launch_bounds__(320) void h3_kernel(const float* __restrict__ h2,
                                                 const float* __restrict__ Wr2,
                                                 const float* __restrict__ bred2,
                                                 const float* __restrict__ pe3,
                                                 float* __restrict__ h3) {
    __shared__ float hrow[128];
    int row = blockIdx.x;
    int b = row >> 7, i = row & 127;
    int r = threadIdx.x;
    if (r < 128) hrow[r] = h2[row * 128 + r];
    __syncthreads();
    float acc = bred2[r];
    const float4* w = (const float4*)(Wr2 + ((size_t)b * 320 + r) * 128);
#pragma unroll
    for (int j4 = 0; j4 < 32; ++j4) {
        float4 wv = w[j4];
        float4 hv = *(const float4*)&hrow[j4 * 4];
        acc = fmaf(hv.x, wv.x, acc);
        acc = fmaf(hv.y, wv.y, acc);
        acc = fmaf(hv.z, wv.z, acc);
        acc = fmaf(hv.w, wv.w, acc);
    }
    h3[(size_t)row * 320 + r] = fmaxf(acc, 0.f) + pe3[i * 320 + r];
}

// ---------------------------------------------------------------------------
// h4: h4b[row,u] = bf16(relu(sum_r2 h3[row,r2]*W_up1[u,r2] + b_up1[u]))
__global__ __launch_bounds__(320) void h4_kernel(const float* __restrict__ h3,
                                                 const float* __restrict__ Wup1,
                                                 const float* __restrict__ bup1,
                                                 unsigned short* __restrict__ h4b) {
    __shared__ float hs[8 * 320];
    int rowbase = blockIdx.x * 8;
    int t = threadIdx.x;
    for (int idx = t; idx < 8 * 320; idx += 320) hs[idx] = h3[(size_t)rowbase * 320 + idx];
    __syncthreads();
    for (int uu = 0; uu < 2; ++uu) {
        int u = t + uu * 320;
        float bias = bup1[u];
        float acc[8];
#pragma unroll
        for (int q = 0; q < 8; ++q) acc[q] = bias;
        const float4* w = (const float4*)(Wup1 + (size_t)u * 320);
        for (int j4 = 0; j4 < 80; ++j4) {
            float4 wv = w[j4];
#pragma unroll
            for (int q = 0; q < 8; ++q) {
                float4 hv = *(const float4*)&hs[q * 320 + j4 * 4];
                acc[q] = fmaf(hv.x, wv.x, acc[q]);
                acc[q] = fmaf(hv.y, wv.y, acc[q]);
                acc[q] = fmaf(hv.z, wv.z, acc[q]);
                acc[q] = fmaf(hv.w, wv.w, acc[q]);
            }
        }
#pragma unroll
        for (int q = 0; q < 8; ++q)
            h4b[((size_t)rowbase + q) * 640 + u] = f2bf(fmaxf(acc[q], 0.f));
    }
}

// ---------------------------------------------------------------------------
// conv_bf16: fp32 -> bf16, vectorized (float4 in, ushort4 out)
__global__ __launch_bounds__(256) void conv_bf16(const float* __restrict__ src,
                                                 unsigned short* __restrict__ dst,
                                                 int n4) {
    int stride = gridDim.x * 256;
    for (int i = blockIdx.x * 256 + threadIdx.x; i < n4; i += stride) {
        float4 v = ((const float4*)src)[i];
        ushort4 o;
        o.x = f2bf(v.x); o.y = f2bf(v.y); o.z = f2bf(v.z); o.w = f2bf(v.w);
        ((ushort4*)dst)[i] = o;
    }
}

// ---------------------------------------------------------------------------
// final MFMA kernel:
// out[b,v] = relu(bfin + sum_l Wfin[l]*relu(bup2[v] + sum_u h4[b,l,u]*Wup2[v,u]))
// Block: 256 thr (4 waves, 2x2 quadrants of 64v x 64l). Tile: 128v x 128l, BK=64.
// LDS (bf16): row r = 8 blocks of 8 elems (16 B); logical k-block g stored at
// physical g^(r&7) -> frag ds_read_b128 lands 2-way bank aliased (free, m136).
// Staging: global_load_lds width=16, wave-uniform LDS base + lane*16.
__global__ __launch_bounds__(256) void final_mfma_kernel(
    const unsigned short* __restrict__ h4b,
    const unsigned short* __restrict__ Wup2b,
    const float* __restrict__ bup2,
    const float* __restrict__ Wfin,
    const float* __restrict__ bfin,
    float* __restrict__ out) {
    __shared__ short tile[16384];   // A: bytes [0,16384), B: bytes [16384,32768)
    __shared__ float redbuf[256];

    int t = threadIdx.x;
    int lane = t & 63;
    int w = t >> 6;
    int wv = w >> 1, wl = w & 1;
    int ln = lane & 15, lg = lane >> 4;
    int b = blockIdx.y;
    int v0 = blockIdx.x * 128;

    const char* Ag = (const char*)Wup2b;
    const char* Bg = (const char*)h4b;
    bool isA = (w < 2);
    int seg = (isA ? w : (w - 2)) * 8192;  // byte offset within 16KB half

    f32x4 acc[4][4];
#pragma unroll
    for (int mt = 0; mt < 4; ++mt)
#pragma unroll
        for (int nt = 0; nt < 4; ++nt) acc[mt][nt] = (f32x4){0.f, 0.f, 0.f, 0.f};

    for (int ch = 0; ch < 10; ++ch) {
        int k0 = ch * 64;
        __syncthreads();
#pragma unroll
        for (int s = 0; s < 8; ++s) {
            int F = seg + s * 1024 + lane * 16;       // byte offset in half
            int r = F >> 7;                            // row 0..127
            int g = ((F >> 4) & 7) ^ (r & 7);          // logical k-block
            size_t rowG = isA ? (size_t)(v0 + r) : (size_t)(b * 128 + r);
            const char* gp = (isA ? Ag : Bg) + (rowG * 640 + (size_t)(k0 + g * 8)) * 2;
            char* lp = (char*)tile + (isA ? 0 : 16384) + seg + s * 1024;  // uniform
            GLDS16(gp, lp);
        }
        __syncthreads();
#pragma unroll
        for (int ks = 0; ks < 2; ++ks) {
            bf16x8 aF[4], bF[4];
#pragma unroll
            for (int mt = 0; mt < 4; ++mt) {
                int rA = wv * 64 + mt * 16 + ln;
                int g = ks * 4 + lg;
                int off = rA * 128 + ((g ^ (rA & 7)) * 16);
                aF[mt] = *(const bf16x8*)((const char*)tile + off);
            }
#pragma unroll
            for (int nt = 0; nt < 4; ++nt) {
                int rB = wl * 64 + nt * 16 + ln;
                int g = ks * 4 + lg;
                int off = 16384 + rB * 128 + ((g ^ (rB & 7)) * 16);
                bF[nt] = *(const bf16x8*)((const char*)tile + off);
            }
#pragma unroll
            for (int mt = 0; mt < 4; ++mt)
#pragma unroll
                for (int nt = 0; nt < 4; ++nt)
                    acc[mt][nt] = __builtin_amdgcn_mfma_f32_16x16x32_bf16(
                        aF[mt], bF[nt], acc[mt][nt], 0, 0, 0);
        }
    }

    // Epilogue: C/D layout col(l)=lane&15, row(v)=(lane>>4)*4+reg  [m89/m91]
    float bfin0 = bfin[0];
#pragma unroll
    for (int mt = 0; mt < 4; ++mt) {
        float bu[4];
#pragma unroll
        for (int r = 0; r < 4; ++r)
            bu[r] = bup2[v0 + wv * 64 + mt * 16 + lg * 4 + r];
        float part[4] = {0.f, 0.f, 0.f, 0.f};
#pragma unroll
        for (int nt = 0; nt < 4; ++nt) {
            float wf = Wfin[wl * 64 + nt * 16 + ln];
#pragma unroll
            for (int r = 0; r < 4; ++r)
                part[r] += wf * fmaxf(acc[mt][nt][r] + bu[r], 0.f);
        }
#pragma unroll
        for (int off = 8; off >= 1; off >>= 1)
#pragma unroll
            for (int r = 0; r < 4; ++r) part[r] += __shfl_xor(part[r], off, 64);
        if (ln == 0) {
#pragma unroll
            for (int r = 0; r < 4; ++r)
                redbuf[wl * 128 + wv * 64 + mt * 16 + lg * 4 + r] = part[r];
        }
    }
    __syncthreads();
    if (t < 128) {
        float vsum = redbuf[t] + redbuf[128 + t] + bfin0;
        out[(size_t)b * 32000 + v0 + t] = fmaxf(vsum, 0.f);
    }
}

// ---------------------------------------------------------------------------
extern "C" void kernel_launch(void* const* d_in, const int* in_sizes, int n_in,
                              void* d_out, int out_size, void* d_ws, size_t ws_size,
                              hipStream_t stream) {
    const float* x      = (const float*)d_in[0];
    const float* W_emb  = (const float*)d_in[1];
    const float* b_emb  = (const float*)d_in[2];
    const float* W_pos1 = (const float*)d_in[3];
    const float* b_pos1 = (const float*)d_in[4];
    const float* W_red  = (const float*)d_in[5];
    const float* b_red  = (const float*)d_in[6];
    const float* W_pos2 = (const float*)d_in[7];
    const float* b_pos2 = (const float*)d_in[8];
    const float* W_red2 = (const float*)d_in[9];
    const float* b_red2 = (const float*)d_in[10];
    const float* W_pos3 = (const float*)d_in[11];
    const float* b_pos3 = (const float*)d_in[12];
    const float* W_up1  = (const float*)d_in[13];
    const float* b_up1  = (const float*)d_in[14];
    const float* W_up2  = (const float*)d_in[15];
    const float* b_up2  = (const float*)d_in[16];
    const float* W_fin  = (const float*)d_in[17];
    const float* b_fin  = (const float*)d_in[18];
    float* out = (float*)d_out;

    float* ws  = (float*)d_ws;
    float* pe1 = ws;                 // 8192
    float* pe2 = pe1 + 8192;         // 16384
    float* pe3 = pe2 + 16384;        // 40960
    float* h1  = pe3 + 40960;        // 65536
    float* s1  = h1 + 65536;         // 1024
    float* Wr1 = s1 + 1024;          // 65536
    float* h2  = Wr1 + 65536;        // 131072
    float* s2  = h2 + 131072;        // 1024
    float* Wr2 = s2 + 1024;          // 327680
    float* h3  = Wr2 + 327680;       // 327680
    float* partA = h3 + 327680;      // 524288
    unsigned short* h4b   = (unsigned short*)(partA + 524288);           // 655360 bf16
    unsigned short* Wup2b = (unsigned short*)(partA + 524288 + 327680);  // 20,480,000 bf16
    // total ws use ~48.3 MB

    pe_kernel<<<dim3(128), 256, 0, stream>>>(W_pos1, b_pos1, pe1, 64, 128);
    pe_kernel<<<dim3(128), 256, 0, stream>>>(W_pos2, b_pos2, pe2, 128, 256);
    pe_kernel<<<dim3(128), 256, 0, stream>>>(W_pos3, b_pos3, pe3, 320, 640);
    conv_bf16<<<dim3(4096), 256, 0, stream>>>(W_up2, Wup2b, (V_ * UP_) / 4);
    embA_kernel<<<dim3(32, 8), 256, 0, stream>>>(x, W_emb, partA);
    reduceA_kernel<<<dim3(1024), 64, 0, stream>>>(partA, b_emb, pe1, h1, s1);
    wr1_kernel<<<dim3(128), 64, 0, stream>>>(W_red, s1, Wr1);
    h2_kernel<<<dim3(1024), 128, 0, stream>>>(h1, Wr1, b_red, pe2, h2, s2);
    wr2_kernel<<<dim3(320), 128, 0, stream>>>(W_red2, s2, Wr2);
    h3_kernel<<<dim3(1024), 320, 0, stream>>>(h2, Wr2, b_red2, pe3, h3);
    h4_kernel<<<dim3(128), 320, 0, stream>>>(h3, W_up1, b_up1, h4b);
    final_mfma_kernel<<<dim3(250, 8), 256, 0, stream>>>(h4b, Wup2b, b_up2, W_fin,
                                                        b_fin, out);
}

// Round 3
// 534.344 us; speedup vs baseline: 2.8732x; 1.3851x over previous
//
#include <hip/hip_runtime.h>
#include <hip/hip_bf16.h>
#include <math.h>

// Problem constants
#define B_  8
#define L_  128
#define V_  32000
#define D_  64
#define R1_ 128
#define R2_ 320
#define UP_ 640
#define SPLITS_ 50   // k-splits for stage A

typedef short bf16x8 __attribute__((ext_vector_type(8)));
typedef float f32x4 __attribute__((ext_vector_type(4)));

#define GLDS16(gp, lp)                                                         \
    __builtin_amdgcn_global_load_lds(                                          \
        (const __attribute__((address_space(1))) void*)(gp),                   \
        (__attribute__((address_space(3))) void*)(lp), 16, 0, 0)

static __device__ inline unsigned short f2bf(float x) {
    __hip_bfloat16 h = __float2bfloat16(x);
    return *reinterpret_cast<unsigned short*>(&h);
}

// hi/lo bf16 split: v ~= hi + lo with rel err ~2^-17
static __device__ inline void split1(float v, unsigned short& h, unsigned short& l) {
    unsigned short hb = f2bf(v);
    float hf = __uint_as_float(((unsigned int)hb) << 16);
    h = hb;
    l = f2bf(v - hf);
}
static __device__ inline void split4(float4 v, ushort4& h, ushort4& l) {
    split1(v.x, h.x, l.x);
    split1(v.y, h.y, l.y);
    split1(v.z, h.z, l.z);
    split1(v.w, h.w, l.w);
}

// ---------------------------------------------------------------------------
// pe_kernel: out[l,o] = relu(b[o] + sum_m P[l,m]*W[o,m]) with P = pos_enc(L,dEnc)
__global__ __launch_bounds__(256) void pe_kernel(const float* __restrict__ W,
                                                 const float* __restrict__ bias,
                                                 float* __restrict__ out,
                                                 int outF, int dEnc) {
    __shared__ float P[640];
    int l = blockIdx.x;
    int t = threadIdx.x;
    for (int m = t; m < dEnc; m += 256) {
        int i = m >> 1;
        float ang = (float)l * powf(10000.0f, -2.0f * (float)i / (float)dEnc);
        P[m] = (m & 1) ? cosf(ang) : sinf(ang);
    }
    __syncthreads();
    for (int o = t; o < outF; o += 256) {
        float acc = bias[o];
        const float* w = W + (size_t)o * dEnc;
        for (int m = 0; m < dEnc; ++m) acc = fmaf(P[m], w[m], acc);
        out[l * outF + o] = fmaxf(acc, 0.f);
    }
}

// ---------------------------------------------------------------------------
// Stage A via MFMA with 3-product bf16 split (fp32-equivalent accuracy).
// partA[split][row][d] = sum_{k in split} x[row,k]*W_emb[d,k]
// grid: (16 rowblocks of 64, SPLITS_), block 256 (4 waves; wave w -> rows 16w..16w+15)
// LDS (shorts): [arr: xh,xl,wh,wl][kblock g 0..7][row 0..63][8] -> 32 KB
__global__ __launch_bounds__(256) void embA_mfma(const float* __restrict__ x,
                                                 const float* __restrict__ Wemb,
                                                 float* __restrict__ partA) {
    __shared__ short lds[16384];
    const int XH = 0, XL = 4096, WH = 8192, WL = 12288;

    int t = threadIdx.x;
    int lane = t & 63, w = t >> 6;
    int ln = lane & 15, lg = lane >> 4;
    int sr = t >> 2, sc = t & 3;   // staging: row 0..63, quarter 0..3
    int rb = blockIdx.x, ks = blockIdx.y;
    int row0 = rb * 64;
    int mrow = w * 16 + ln;

    f32x4 acc[4];
#pragma unroll
    for (int nt = 0; nt < 4; ++nt) acc[nt] = (f32x4){0.f, 0.f, 0.f, 0.f};

    for (int ch = 0; ch < 640 / 64; ++ch) {
        int k0 = ks * 640 + ch * 64;
        const float* xrow = x + (size_t)(row0 + sr) * 32000 + k0;
        const float* wrow = Wemb + (size_t)sr * 32000 + k0;
        __syncthreads();
#pragma unroll
        for (int i = 0; i < 4; ++i) {
            int k = sc * 4 + 16 * i;           // 0..63
            int idx = ((k >> 3) * 64 + sr) * 8 + (k & 7);
            float4 v = *(const float4*)(xrow + k);
            ushort4 h, l;
            split4(v, h, l);
            *(ushort4*)&lds[XH + idx] = h;
            *(ushort4*)&lds[XL + idx] = l;
            float4 wv = *(const float4*)(wrow + k);
            split4(wv, h, l);
            *(ushort4*)&lds[WH + idx] = h;
            *(ushort4*)&lds[WL + idx] = l;
        }
        __syncthreads();
#pragma unroll
        for (int kstep = 0; kstep < 2; ++kstep) {
            int ga = kstep * 4 + lg;
            bf16x8 ah = *(const bf16x8*)&lds[XH + (ga * 64 + mrow) * 8];
            bf16x8 al = *(const bf16x8*)&lds[XL + (ga * 64 + mrow) * 8];
#pragma unroll
            for (int nt = 0; nt < 4; ++nt) {
                int nrow = nt * 16 + ln;
                bf16x8 bh = *(const bf16x8*)&lds[WH + (ga * 64 + nrow) * 8];
                bf16x8 bl = *(const bf16x8*)&lds[WL + (ga * 64 + nrow) * 8];
                acc[nt] = __builtin_amdgcn_mfma_f32_16x16x32_bf16(ah, bh, acc[nt], 0, 0, 0);
                acc[nt] = __builtin_amdgcn_mfma_f32_16x16x32_bf16(ah, bl, acc[nt], 0, 0, 0);
                acc[nt] = __builtin_amdgcn_mfma_f32_16x16x32_bf16(al, bh, acc[nt], 0, 0, 0);
            }
        }
    }
    // C/D: col(n=d)=lane&15, row(m=x-row)=(lane>>4)*4+reg
#pragma unroll
    for (int nt = 0; nt < 4; ++nt)
#pragma unroll
        for (int r = 0; r < 4; ++r)
            partA[((size_t)ks * 1024 + row0 + w * 16 + lg * 4 + r) * 64 + nt * 16 + ln] =
                acc[nt][r];
}

// ---------------------------------------------------------------------------
// reduceA: h1[row,d] = relu(sum_s partA + b_emb[d]) + pe1[l,d]; s1[row]=sum_d h1
__global__ __launch_bounds__(64) void reduceA_kernel(const float* __restrict__ partA,
                                                     const float* __restrict__ bemb,
                                                     const float* __restrict__ pe1,
                                                     float* __restrict__ h1,
                                                     float* __restrict__ s1) {
    int row = blockIdx.x;
    int d = threadIdx.x;
    int l = row & 127;
    float v = bemb[d];
    for (int s = 0; s < SPLITS_; ++s) v += partA[((size_t)s * 1024 + row) * 64 + d];
    v = fmaxf(v, 0.f) + pe1[l * 64 + d];
    h1[row * 64 + d] = v;
    float sum = v;
    for (int off = 32; off > 0; off >>= 1) sum += __shfl_down(sum, off);
    if (d == 0) s1[row] = sum;
}

// ---------------------------------------------------------------------------
// wr1: Wr1[b,r,j] = sum_k s1[b,k] * W_red[r, k*64+j]
__global__ __launch_bounds__(64) void wr1_kernel(const float* __restrict__ Wred,
                                                 const float* __restrict__ s1,
                                                 float* __restrict__ Wr1) {
    __shared__ float ss[8 * 128];
    int r = blockIdx.x;
    int j = threadIdx.x;
    for (int idx = j; idx < 1024; idx += 64) ss[idx] = s1[idx];
    __syncthreads();
    float acc[8];
#pragma unroll
    for (int b = 0; b < 8; ++b) acc[b] = 0.f;
    const float* w = Wred + (size_t)r * 8192 + j;
    for (int k = 0; k < 128; ++k) {
        float wv = w[k * 64];
#pragma unroll
        for (int b = 0; b < 8; ++b) acc[b] = fmaf(ss[b * 128 + k], wv, acc[b]);
    }
#pragma unroll
    for (int b = 0; b < 8; ++b) Wr1[((size_t)b * 128 + r) * 64 + j] = acc[b];
}

// ---------------------------------------------------------------------------
// h2: h2[b,i,r] = relu(sum_j h1[b,i,j]*Wr1[b,r,j] + b_red[r]) + pe2[i,r]; s2=sum_r
__global__ __launch_bounds__(128) void h2_kernel(const float* __restrict__ h1,
                                                 const float* __restrict__ Wr1,
                                                 const float* __restrict__ bred,
                                                 const float* __restrict__ pe2,
                                                 float* __restrict__ h2,
                                                 float* __restrict__ s2) {
    __shared__ float hrow[64];
    __shared__ float red[2];
    int row = blockIdx.x;
    int b = row >> 7, i = row & 127;
    int r = threadIdx.x;
    if (r < 64) hrow[r] = h1[row * 64 + r];
    __syncthreads();
    float acc = bred[r];
    const float4* w = (const float4*)(Wr1 + ((size_t)b * 128 + r) * 64);
#pragma unroll
    for (int j4 = 0; j4 < 16; ++j4) {
        float4 wv = w[j4];
        float4 hv = *(const float4*)&hrow[j4 * 4];
        acc = fmaf(hv.x, wv.x, acc);
        acc = fmaf(hv.y, wv.y, acc);
        acc = fmaf(hv.z, wv.z, acc);
        acc = fmaf(hv.w, wv.w, acc);
    }
    float val = fmaxf(acc, 0.f) + pe2[i * 128 + r];
    h2[row * 128 + r] = val;
    float sum = val;
    for (int off = 32; off > 0; off >>= 1) sum += __shfl_down(sum, off);
    if ((r & 63) == 0) red[r >> 6] = sum;
    __syncthreads();
    if (r == 0) s2[row] = red[0] + red[1];
}

// ---------------------------------------------------------------------------
// wr2: Wr2[b,r2,j] = sum_k s2[b,k] * W_red2[r2, k*128+j]
__global__ __launch_bounds__(128) void wr2_kernel(const float* __restrict__ Wred2,
                                                  const float* __restrict__ s2,
                                                  float* __restrict__ Wr2) {
    __shared__ float ss[8 * 128];
    int r = blockIdx.x;
    int j = threadIdx.x;
    for (int idx = j; idx < 1024; idx += 128) ss[idx] = s2[idx];
    __syncthreads();
    float acc[8];
#pragma unroll
    for (int b = 0; b < 8; ++b) acc[b] = 0.f;
    const float* w = Wred2 + (size_t)r * 16384 + j;
    for (int k = 0; k < 128; ++k) {
        float wv = w[k * 128];
#pragma unroll
        for (int b = 0; b < 8; ++b) acc[b] = fmaf(ss[b * 128 + k], wv, acc[b]);
    }
#pragma unroll
    for (int b = 0; b < 8; ++b) Wr2[((size_t)b * 320 + r) * 128 + j] = acc[b];
}

// ---------------------------------------------------------------------------
// h3: h3[b,i,r2] = relu(sum_j h2[b,i,j]*Wr2[b,r2,j] + b_red2[r2]) + pe3[i,r2]
__global__ __launch_bounds__(320) void h3_kernel(const float* __restrict__ h2,
                                                 const float* __restrict__ Wr2,
                                                 const float* __restrict__ bred2,
                                                 const float* __restrict__ pe3,
                                                 float* __restrict__ h3) {
    __shared__ float hrow[128];
    int row = blockIdx.x;
    int b = row >> 7, i = row & 127;
    int r = threadIdx.x;
    if (r < 128) hrow[r] = h2[row * 128 + r];
    __syncthreads();
    float acc = bred2[r];
    const float4* w = (const float4*)(Wr2 + ((size_t)b * 320 + r) * 128);
#pragma unroll
    for (int j4 = 0; j4 < 32; ++j4) {
        float4 wv = w[j4];
        float4 hv = *(const float4*)&hrow[j4 * 4];
        acc = fmaf(hv.x, wv.x, acc);
        acc = fmaf(hv.y, wv.y, acc);
        acc = fmaf(hv.z, wv.z, acc);
        acc = fmaf(hv.w, wv.w, acc);
    }
    h3[(size_t)row * 320 + r] = fmaxf(acc, 0.f) + pe3[i * 320 + r];
}

// ---------------------------------------------------------------------------
// h4: h4b[row,u] = bf16(relu(sum_r2 h3[row,r2]*W_up1[u,r2] + b_up1[u]))
__global__ __launch_bounds__(320) void h4_kernel(const float* __restrict__ h3,
                                                 const float* __restrict__ Wup1,
                                                 const float* __restrict__ bup1,
                                                 unsigned short* __restrict__ h4b) {
    __shared__ float hs[8 * 320];
    int rowbase = blockIdx.x * 8;
    int t = threadIdx.x;
    for (int idx = t; idx < 8 * 320; idx += 320) hs[idx] = h3[(size_t)rowbase * 320 + idx];
    __syncthreads();
    for (int uu = 0; uu < 2; ++uu) {
        int u = t + uu * 320;
        float bias = bup1[u];
        float acc[8];
#pragma unroll
        for (int q = 0; q < 8; ++q) acc[q] = bias;
        const float4* w = (const float4*)(Wup1 + (size_t)u * 320);
        for (int j4 = 0; j4 < 80; ++j4) {
            float4 wv = w[j4];
#pragma unroll
            for (int q = 0; q < 8; ++q) {
                float4 hv = *(const float4*)&hs[q * 320 + j4 * 4];
                acc[q] = fmaf(hv.x, wv.x, acc[q]);
                acc[q] = fmaf(hv.y, wv.y, acc[q]);
                acc[q] = fmaf(hv.z, wv.z, acc[q]);
                acc[q] = fmaf(hv.w, wv.w, acc[q]);
            }
        }
#pragma unroll
        for (int q = 0; q < 8; ++q)
            h4b[((size_t)rowbase + q) * 640 + u] = f2bf(fmaxf(acc[q], 0.f));
    }
}

// ---------------------------------------------------------------------------
// conv_bf16: fp32 -> bf16, vectorized (float4 in, ushort4 out)
__global__ __launch_bounds__(256) void conv_bf16(const float* __restrict__ src,
                                                 unsigned short* __restrict__ dst,
                                                 int n4) {
    int stride = gridDim.x * 256;
    for (int i = blockIdx.x * 256 + threadIdx.x; i < n4; i += stride) {
        float4 v = ((const float4*)src)[i];
        ushort4 o;
        o.x = f2bf(v.x); o.y = f2bf(v.y); o.z = f2bf(v.z); o.w = f2bf(v.w);
        ((ushort4*)dst)[i] = o;
    }
}

// ---------------------------------------------------------------------------
// final MFMA kernel:
// out[b,v] = relu(bfin + sum_l Wfin[l]*relu(bup2[v] + sum_u h4[b,l,u]*Wup2[v,u]))
__global__ __launch_bounds__(256) void final_mfma_kernel(
    const unsigned short* __restrict__ h4b,
    const unsigned short* __restrict__ Wup2b,
    const float* __restrict__ bup2,
    const float* __restrict__ Wfin,
    const float* __restrict__ bfin,
    float* __restrict__ out) {
    __shared__ short tile[16384];   // A: bytes [0,16384), B: bytes [16384,32768)
    __shared__ float redbuf[256];

    int t = threadIdx.x;
    int lane = t & 63;
    int w = t >> 6;
    int wv = w >> 1, wl = w & 1;
    int ln = lane & 15, lg = lane >> 4;
    int b = blockIdx.y;
    int v0 = blockIdx.x * 128;

    const char* Ag = (const char*)Wup2b;
    const char* Bg = (const char*)h4b;
    bool isA = (w < 2);
    int seg = (isA ? w : (w - 2)) * 8192;  // byte offset within 16KB half

    f32x4 acc[4][4];
#pragma unroll
    for (int mt = 0; mt < 4; ++mt)
#pragma unroll
        for (int nt = 0; nt < 4; ++nt) acc[mt][nt] = (f32x4){0.f, 0.f, 0.f, 0.f};

    for (int ch = 0; ch < 10; ++ch) {
        int k0 = ch * 64;
        __syncthreads();
#pragma unroll
        for (int s = 0; s < 8; ++s) {
            int F = seg + s * 1024 + lane * 16;       // byte offset in half
            int r = F >> 7;                            // row 0..127
            int g = ((F >> 4) & 7) ^ (r & 7);          // logical k-block
            size_t rowG = isA ? (size_t)(v0 + r) : (size_t)(b * 128 + r);
            const char* gp = (isA ? Ag : Bg) + (rowG * 640 + (size_t)(k0 + g * 8)) * 2;
            char* lp = (char*)tile + (isA ? 0 : 16384) + seg + s * 1024;  // uniform
            GLDS16(gp, lp);
        }
        __syncthreads();
#pragma unroll
        for (int ks = 0; ks < 2; ++ks) {
            bf16x8 aF[4], bF[4];
#pragma unroll
            for (int mt = 0; mt < 4; ++mt) {
                int rA = wv * 64 + mt * 16 + ln;
                int g = ks * 4 + lg;
                int off = rA * 128 + ((g ^ (rA & 7)) * 16);
                aF[mt] = *(const bf16x8*)((const char*)tile + off);
            }
#pragma unroll
            for (int nt = 0; nt < 4; ++nt) {
                int rB = wl * 64 + nt * 16 + ln;
                int g = ks * 4 + lg;
                int off = 16384 + rB * 128 + ((g ^ (rB & 7)) * 16);
                bF[nt] = *(const bf16x8*)((const char*)tile + off);
            }
#pragma unroll
            for (int mt = 0; mt < 4; ++mt)
#pragma unroll
                for (int nt = 0; nt < 4; ++nt)
                    acc[mt][nt] = __builtin_amdgcn_mfma_f32_16x16x32_bf16(
                        aF[mt], bF[nt], acc[mt][nt], 0, 0, 0);
        }
    }

    // Epilogue: C/D layout col(l)=lane&15, row(v)=(lane>>4)*4+reg
    float bfin0 = bfin[0];
#pragma unroll
    for (int mt = 0; mt < 4; ++mt) {
        float bu[4];
#pragma unroll
        for (int r = 0; r < 4; ++r)
            bu[r] = bup2[v0 + wv * 64 + mt * 16 + lg * 4 + r];
        float part[4] = {0.f, 0.f, 0.f, 0.f};
#pragma unroll
        for (int nt = 0; nt < 4; ++nt) {
            float wf = Wfin[wl * 64 + nt * 16 + ln];
#pragma unroll
            for (int r = 0; r < 4; ++r)
                part[r] += wf * fmaxf(acc[mt][nt][r] + bu[r], 0.f);
        }
#pragma unroll
        for (int off = 8; off >= 1; off >>= 1)
#pragma unroll
            for (int r = 0; r < 4; ++r) part[r] += __shfl_xor(part[r], off, 64);
        if (ln == 0) {
#pragma unroll
            for (int r = 0; r < 4; ++r)
                redbuf[wl * 128 + wv * 64 + mt * 16 + lg * 4 + r] = part[r];
        }
    }
    __syncthreads();
    if (t < 128) {
        float vsum = redbuf[t] + redbuf[128 + t] + bfin0;
        out[(size_t)b * 32000 + v0 + t] = fmaxf(vsum, 0.f);
    }
}

// ---------------------------------------------------------------------------
extern "C" void kernel_launch(void* const* d_in, const int* in_sizes, int n_in,
                              void* d_out, int out_size, void* d_ws, size_t ws_size,
                              hipStream_t stream) {
    const float* x      = (const float*)d_in[0];
    const float* W_emb  = (const float*)d_in[1];
    const float* b_emb  = (const float*)d_in[2];
    const float* W_pos1 = (const float*)d_in[3];
    const float* b_pos1 = (const float*)d_in[4];
    const float* W_red  = (const float*)d_in[5];
    const float* b_red  = (const float*)d_in[6];
    const float* W_pos2 = (const float*)d_in[7];
    const float* b_pos2 = (const float*)d_in[8];
    const float* W_red2 = (const float*)d_in[9];
    const float* b_red2 = (const float*)d_in[10];
    const float* W_pos3 = (const float*)d_in[11];
    const float* b_pos3 = (const float*)d_in[12];
    const float* W_up1  = (const float*)d_in[13];
    const float* b_up1  = (const float*)d_in[14];
    const float* W_up2  = (const float*)d_in[15];
    const float* b_up2  = (const float*)d_in[16];
    const float* W_fin  = (const float*)d_in[17];
    const float* b_fin  = (const float*)d_in[18];
    float* out = (float*)d_out;

    float* ws  = (float*)d_ws;
    float* pe1 = ws;                 // 8192
    float* pe2 = pe1 + 8192;         // 16384
    float* pe3 = pe2 + 16384;        // 40960
    float* h1  = pe3 + 40960;        // 65536
    float* s1  = h1 + 65536;         // 1024
    float* Wr1 = s1 + 1024;          // 65536
    float* h2  = Wr1 + 65536;        // 131072
    float* s2  = h2 + 131072;        // 1024
    float* Wr2 = s2 + 1024;          // 327680
    float* h3  = Wr2 + 327680;       // 327680
    unsigned short* h4b   = (unsigned short*)(h3 + 327680);          // 655360 shorts
    unsigned short* Wup2b = (unsigned short*)((float*)h4b + 327680); // 20,480,000 shorts
    // partA (50*1024*64 = 3.28M floats = 13.1 MB) aliases the Wup2b region:
    // it is dead after reduceA, and conv_bf16 (which writes Wup2b) launches after.
    float* partA = (float*)Wup2b;
    // total ws use ~46 MB (same footprint as round 2)

    pe_kernel<<<dim3(128), 256, 0, stream>>>(W_pos1, b_pos1, pe1, 64, 128);
    pe_kernel<<<dim3(128), 256, 0, stream>>>(W_pos2, b_pos2, pe2, 128, 256);
    pe_kernel<<<dim3(128), 256, 0, stream>>>(W_pos3, b_pos3, pe3, 320, 640);
    embA_mfma<<<dim3(16, SPLITS_), 256, 0, stream>>>(x, W_emb, partA);
    reduceA_kernel<<<dim3(1024), 64, 0, stream>>>(partA, b_emb, pe1, h1, s1);
    conv_bf16<<<dim3(4096), 256, 0, stream>>>(W_up2, Wup2b, (V_ * UP_) / 4);
    wr1_kernel<<<dim3(128), 64, 0, stream>>>(W_red, s1, Wr1);
    h2_kernel<<<dim3(1024), 128, 0, stream>>>(h1, Wr1, b_red, pe2, h2, s2);
    wr2_kernel<<<dim3(320), 128, 0, stream>>>(W_red2, s2, Wr2);
    h3_kernel<<<dim3(1024), 320, 0, stream>>>(h2, Wr2, b_red2, pe3, h3);
    h4_kernel<<<dim3(128), 320, 0, stream>>>(h3, W_up1, b_up1, h4b);
    final_mfma_kernel<<<dim3(250, 8), 256, 0, stream>>>(h4b, Wup2b, b_up2, W_fin,
                                                        b_fin, out);
}